// Round 25
// baseline (883.852 us; speedup 1.0000x reference)
//
#include <hip/hip_runtime.h>

// Problem constants (shapes fixed by the reference)
#define HP    1017
#define WP    1017
#define NPIX  (HP*WP)          // 1034289
#define N3    (NPIX/3)         // 344763 = 339*WP -> all flat-boundary pixels at col 0 / WP-1
#define W_IMG 1024
#define EPSV  1e-7f

// temporal blocking geometry: SQUARE tile, 64x64, K=4
#define K_ITERS 4
#define RY   48
#define CW   48
#define HALO 8
#define IY   64
#define IC   64
#define NBX  22                // 22*48 = 1056 >= 1017
#define NBY  22
#define TBT  512
#define NSLOT 8                // 64*64 = 4096 = 512*8
#define WQMAX 1551431

typedef _Float16 half_t;

__device__ __forceinline__ float fast_rcp(float x) { return __builtin_amdgcn_rcpf(x); }

// ---------------------------------------------------------------------------
// init: t0 = tlb = max_c(1 - center/A), and pack img_c (fp16) contiguously
// ---------------------------------------------------------------------------
__global__ void init_kernel(const float* __restrict__ img, const float* __restrict__ A,
                            half_t* __restrict__ img_c, float* __restrict__ t0) {
    int b = blockIdx.x * blockDim.x + threadIdx.x;
    int a = blockIdx.y;
    if (b >= WP) return;
    int m = a * WP + b;
    float A0 = A[0], A1 = A[1], A2 = A[2];
    const float* src = img + ((size_t)a * W_IMG + b) * 3;
    img_c[3*m+0] = (half_t)src[0];
    img_c[3*m+1] = (half_t)src[1];
    img_c[3*m+2] = (half_t)src[2];
    const float* cen = img + ((size_t)(a+3) * W_IMG + (b+3)) * 3;
    float t = 1.0f - cen[0] / A0;
    t = fmaxf(t, 1.0f - cen[1] / A1);
    t = fmaxf(t, 1.0f - cen[2] / A2);
    t0[m] = t;
}

// ---------------------------------------------------------------------------
// temporal-blocked kernel: 4 GD iterations in LDS.
// R24 structure (reduced barriers, f32 LDS buffers) + boundary handling in
// pass B hoisted behind b==0 / b==WP-1 (exec-masked, skipped by interior
// waves). rm/rp are unconditional LDS reads, overridden only at the two
// image-edge columns (the only places m==0 / m==NPIX-1 / flat fixes occur).
// ---------------------------------------------------------------------------
__global__ __launch_bounds__(TBT, 4) void tb_kernel(
    const float* __restrict__ tin, float* __restrict__ tout,
    const half_t* __restrict__ img_c, const float* __restrict__ A)
{
    __shared__ float lgl[2][IY][IC];    // 32 KiB (ping-pong per level)
    __shared__ float sgl[2][IY][IC];    // 32 KiB (ping-pong per level)
    __shared__ float rll[IY][IC];       // 16 KiB  => 80 KiB total, 2 blocks/CU

    const int tid   = threadIdx.x;
    const int i0    = tid >> 6;         // 0..7 = wave id; wave w owns rows i with i&7==w
    const int j     = tid & 63;         // lane = fixed column
    const int rbase = blockIdx.y * RY - HALO;
    const int cbase = blockIdx.x * CW - HALO;
    const int col   = cbase + j;
    const float A0 = A[0], A1 = A[1], A2 = A[2];

    // hoisted column-wrap: cell (i,j) is flat pixel (arow+da, b)
    const int da = (col < 0) ? -1 : ((col >= WP) ? 1 : 0);
    const int b  = col - da * WP;
    const bool bW  = (b >= 1), bW2 = (b >= 2);
    const bool bE  = (b <= WP-2), bE2 = (b <= WP-3);
    const bool edgeL = (b == 0);        // only lanes that can hit flat-left fixes
    const bool edgeR = (b == WP-1);     // only lanes that can hit flat-right fixes
    const int m00 = (rbase + i0) * WP + col;

    const unsigned* imgw = (const unsigned*)img_c;
    unsigned pk01[NSLOT], pk12[NSLOT], pk3[NSLOT/2];
    float w0r[NSLOT];                   // guard(t) at own cell
    float rB[NSLOT];                    // rcp(raw t) at own cell (f32)

    // ---- load t_k -> lg + r + regs; stage img window into registers ----
    // No barrier after: B(0) reads only row-i rll (own wave) + registers.
    {
        int m = m00;
        #pragma unroll
        for (int s = 0; s < NSLOT; ++s, m += 8*WP) {
            int i = i0 + 8*s;
            float v = 1.0f;
            if ((unsigned)m < (unsigned)NPIX) v = tin[m];
            float rv = fast_rcp(v);
            w0r[s] = (v <= 0.0f) ? EPSV : v;
            rB[s]  = rv;
            rll[i][j]    = rv;
            lgl[0][i][j] = __logf(v <= 0.0f ? EPSV : v);
            // img window: halfs 3m-1 .. 3m+3 pre-arranged by parity
            int hb = 3*m - 1;
            int wq, off0;
            if (m <= 0) { wq = 0; off0 = 0; }
            else        { wq = hb >> 1; off0 = 1 + (hb & 1); if (wq > WQMAX) wq = WQMAX; }
            unsigned w0 = imgw[wq], w1 = imgw[wq+1], w2 = imgw[wq+2];
            unsigned pa, pb; unsigned f3h;
            if (off0 == 0)      { pa = (w0 & 0xffffu) | (w0 << 16); pb = (w0 >> 16) | (w1 << 16); f3h = w2 & 0xffffu; }
            else if (off0 == 1) { pa = w0;                          pb = w1;                      f3h = w2 & 0xffffu; }
            else                { pa = (w0 >> 16) | (w1 << 16);     pb = (w1 >> 16) | (w2 << 16); f3h = w2 >> 16; }
            if (m >= NPIX - 1) f3h = (pb >> 16);   // f3 := f2 at the last pixel
            pk01[s] = pa; pk12[s] = pb;
            if (s & 1) pk3[s >> 1] |= (f3h << 16);
            else       pk3[s >> 1]  = f3h;
        }
    }

    #pragma unroll
    for (int lvl = 0; lvl < K_ITERS; ++lvl) {
        float (* __restrict__ lgc)[IC] = lgl[lvl & 1];
        float (* __restrict__ lgn)[IC] = lgl[(lvl & 1) ^ 1];
        float (* __restrict__ sgc)[IC] = sgl[lvl & 1];
        const int ms = 2*lvl + 1;
        const bool jokB = (j >= ms && j < IC - ms);
        // --- pass B: sig from r (own-cell reg, row-i rll neighbors) + staged img ---
        {
            int m = m00;
            #pragma unroll
            for (int s = 0; s < NSLOT; ++s, m += 8*WP) {
                int i = i0 + 8*s;
                float sv = 0.0f;
                if (jokB && i >= ms && i < IY - ms && (unsigned)m < (unsigned)NPIX) {
                    float r0 = rB[s];
                    float rm = rll[i][j-1];     // pixel m-1 (j>=1 since ms>=1)
                    float rp = rll[i][j+1];     // pixel m+1
                    if (edgeL)      { if (m == 0)        rm = r0; }
                    else if (edgeR) { if (m == NPIX - 1) rp = r0; }
                    union { unsigned u; half_t h[2]; } ua, ub, uc;
                    ua.u = pk01[s]; ub.u = pk12[s]; uc.u = pk3[s >> 1];
                    float fm1 = (float)ua.h[0];
                    float f0  = (float)ua.h[1];
                    float f1  = (float)ub.h[0];
                    float f2  = (float)ub.h[1];
                    float f3  = (float)uc.h[s & 1];
                    float dm1 = (fm1 - A2) * rm + A2;
                    float d0  = (f0  - A0) * r0 + A0;
                    float d1  = (f1  - A1) * r0 + A1;
                    float d2  = (f2  - A2) * r0 + A2;
                    float d3  = (f3  - A0) * rp + A0;
                    float y0 = 0.5f * (d1 - dm1);
                    float y1 = 0.5f * (d2 - d0);
                    float y2 = 0.5f * (d3 - d1);
                    // flat-boundary fixes live only at image cols 0 / WP-1
                    if (edgeL) {
                        if (m == 0 || m == N3 || m == 2*N3) y0 = d1 - d0;
                    } else if (edgeR) {
                        if (m == N3-1 || m == 2*N3-1 || m == NPIX-1) y2 = d2 - d1;
                    }
                    float l2 = sqrtf(y0*y0 + y1*y1 + y2*y2);
                    sv = fast_rcp(1.0f + __expf(48.0f * (l2 - 0.1f)));
                }
                sgc[i][j] = sv;
            }
        }
        __syncthreads();   // covers: B's sgl writes -> C's cross-row sgl reads,
                           // and prev C's lgl writes -> this C's cross-row lgl reads
        // --- pass C: t update; w0/r from registers; fully unrolled for ILP ---
        const int mt = 2*lvl + 2;
        const bool jokC = (j >= mt && j < IC - mt);
        {
            int m = m00;
            #pragma unroll
            for (int s = 0; s < NSLOT; ++s, m += 8*WP) {
                int i = i0 + 8*s;
                if (jokC && i >= mt && i < IY - mt && (unsigned)m < (unsigned)NPIX) {
                    int a = rbase + i + da;
                    float lgC = lgc[i][j];
                    float acc = 0.0f;
                    if (bW)
                        acc += (lgC - (bW2 ? lgc[i][j-2] : 0.0f)) * sgc[i][j-1];
                    if (bE)
                        acc -= ((bE2 ? lgc[i][j+2] : 0.0f) - lgC) * sgc[i][j+1];
                    if (a <= HP-2)
                        acc += (lgC - ((a <= HP-3) ? lgc[i+2][j] : 0.0f)) * sgc[i+1][j];
                    if (a >= 1)
                        acc -= (((a >= 2) ? lgc[i-2][j] : 0.0f) - lgC) * sgc[i-1][j];
                    float rr = rB[s];
                    float rw = (rr <= 0.0f) ? 1e7f : rr;    // rcp(guard(t))
                    float v = w0r[s] - 0.001f * 2.0f * acc * rw;
                    if (lvl == K_ITERS - 1) {
                        if (col < WP) tout[m] = v;          // interior => col>=0, m valid
                    } else {
                        float rv = fast_rcp(v);
                        w0r[s] = (v <= 0.0f) ? EPSV : v;
                        rB[s]  = rv;
                        lgn[i][j] = __logf(v <= 0.0f ? EPSV : v);
                        rll[i][j] = rv;
                    }
                }
            }
        }
        // no barrier: next B depends only on same-wave state (rll row i, regs);
        // sgl WAR removed by double-buffer; lgl WAR covered by next B->C barrier
    }
}

// ---------------------------------------------------------------------------
// final dehaze from t_100
// ---------------------------------------------------------------------------
__global__ void out_kernel(const float* __restrict__ t, const half_t* __restrict__ img_c,
                           const float* __restrict__ A, float* __restrict__ out) {
    int m = blockIdx.x * blockDim.x + threadIdx.x;
    if (m >= NPIX) return;
    float tv = t[m];
    float A0 = A[0], A1 = A[1], A2 = A[2];
    float r = 1.0f / tv;               // precise div for the final output
    out[3*m+0] = ((float)img_c[3*m+0] - A0) * r + A0;
    out[3*m+1] = ((float)img_c[3*m+1] - A1) * r + A1;
    out[3*m+2] = ((float)img_c[3*m+2] - A2) * r + A2;
}

extern "C" void kernel_launch(void* const* d_in, const int* in_sizes, int n_in,
                              void* d_out, int out_size, void* d_ws, size_t ws_size,
                              hipStream_t stream) {
    const float* img = (const float*)d_in[0];
    const float* A   = (const float*)d_in[1];
    // workspace: t_a[N] f32 | t_b[N] f32 | img_c[3N] f16 (+slack)
    float*  ws    = (float*)d_ws;
    float*  t_a   = ws;
    float*  t_b   = t_a + NPIX;
    half_t* img_c = (half_t*)(t_b + NPIX);

    dim3 blk2(256, 1, 1);
    dim3 grd2((WP + 255) / 256, HP, 1);
    int blk1 = 256;
    int grd1 = (NPIX + blk1 - 1) / blk1;

    hipLaunchKernelGGL(init_kernel, grd2, blk2, 0, stream, img, A, img_c, t_a);

    float* tsrc = t_a;
    float* tdst = t_b;
    for (int d = 0; d < 25; ++d) {               // 25 dispatches x 4 iters = 100
        hipLaunchKernelGGL(tb_kernel, dim3(NBX, NBY), dim3(TBT), 0, stream,
                           tsrc, tdst, img_c, A);
        float* tmp = tsrc; tsrc = tdst; tdst = tmp;
    }
    hipLaunchKernelGGL(out_kernel, dim3(grd1), dim3(blk1), 0, stream,
                       tsrc, img_c, A, (float*)d_out);
}

// Round 26
// 774.601 us; speedup vs baseline: 1.1410x; 1.1410x over previous
//
#include <hip/hip_runtime.h>

// Problem constants (shapes fixed by the reference)
#define HP    1017
#define WP    1017
#define NPIX  (HP*WP)          // 1034289
#define N3    (NPIX/3)         // 344763
#define W_IMG 1024
#define EPSV  1e-7f

// temporal blocking geometry: SQUARE tile, 64x64, K=4
#define K_ITERS 4
#define RY   48
#define CW   48
#define HALO 8
#define IY   64
#define IC   64
#define NBX  22                // 22*48 = 1056 >= 1017
#define NBY  22
#define TBT  512
#define NSLOT 8                // 64*64 = 4096 = 512*8
#define WQMAX 1551431

typedef _Float16 half_t;

__device__ __forceinline__ float fast_rcp(float x) { return __builtin_amdgcn_rcpf(x); }

// ---------------------------------------------------------------------------
// init: t0 = tlb = max_c(1 - center/A), and pack img_c (fp16) contiguously
// ---------------------------------------------------------------------------
__global__ void init_kernel(const float* __restrict__ img, const float* __restrict__ A,
                            half_t* __restrict__ img_c, float* __restrict__ t0) {
    int b = blockIdx.x * blockDim.x + threadIdx.x;
    int a = blockIdx.y;
    if (b >= WP) return;
    int m = a * WP + b;
    float A0 = A[0], A1 = A[1], A2 = A[2];
    const float* src = img + ((size_t)a * W_IMG + b) * 3;
    img_c[3*m+0] = (half_t)src[0];
    img_c[3*m+1] = (half_t)src[1];
    img_c[3*m+2] = (half_t)src[2];
    const float* cen = img + ((size_t)(a+3) * W_IMG + (b+3)) * 3;
    float t = 1.0f - cen[0] / A0;
    t = fmaxf(t, 1.0f - cen[1] / A1);
    t = fmaxf(t, 1.0f - cen[2] / A2);
    t0[m] = t;
}

// ---------------------------------------------------------------------------
// temporal-blocked kernel: 4 GD iterations in LDS (R24 structure, verbatim).
// Reduced barriers (4/dispatch): row i owned by wave i&7; B depends on prior C
// only through same-wave state; sgl double-buffered removes the cross-wave WAR.
// All LDS buffers f32 (no f16 cvts on the hot paths). 80 KB/block, 2 blocks/CU.
// ---------------------------------------------------------------------------
__global__ __launch_bounds__(TBT, 4) void tb_kernel(
    const float* __restrict__ tin, float* __restrict__ tout,
    const half_t* __restrict__ img_c, const float* __restrict__ A)
{
    __shared__ float lgl[2][IY][IC];    // 32 KiB (ping-pong per level)
    __shared__ float sgl[2][IY][IC];    // 32 KiB (ping-pong per level)
    __shared__ float rll[IY][IC];       // 16 KiB  => 80 KiB total, 2 blocks/CU

    const int tid   = threadIdx.x;
    const int i0    = tid >> 6;         // 0..7 = wave id; wave w owns rows i with i&7==w
    const int j     = tid & 63;         // lane = fixed column
    const int rbase = blockIdx.y * RY - HALO;
    const int cbase = blockIdx.x * CW - HALO;
    const int col   = cbase + j;
    const float A0 = A[0], A1 = A[1], A2 = A[2];

    // hoisted column-wrap: cell (i,j) is flat pixel (arow+da, b)
    const int da = (col < 0) ? -1 : ((col >= WP) ? 1 : 0);
    const int b  = col - da * WP;
    const bool bW  = (b >= 1), bW2 = (b >= 2);
    const bool bE  = (b <= WP-2), bE2 = (b <= WP-3);
    const int m00 = (rbase + i0) * WP + col;

    const unsigned* imgw = (const unsigned*)img_c;
    unsigned pk01[NSLOT], pk12[NSLOT], pk3[NSLOT/2];
    float w0r[NSLOT];                   // guard(t) at own cell
    float rB[NSLOT];                    // rcp(raw t) at own cell (f32)

    // ---- load t_k -> lg + r + regs; stage img window into registers ----
    // No barrier after: B(0) reads only row-i rll (own wave) + registers.
    {
        int m = m00;
        #pragma unroll
        for (int s = 0; s < NSLOT; ++s, m += 8*WP) {
            int i = i0 + 8*s;
            float v = 1.0f;
            if ((unsigned)m < (unsigned)NPIX) v = tin[m];
            float rv = fast_rcp(v);
            w0r[s] = (v <= 0.0f) ? EPSV : v;
            rB[s]  = rv;
            rll[i][j]    = rv;
            lgl[0][i][j] = __logf(v <= 0.0f ? EPSV : v);
            // img window: halfs 3m-1 .. 3m+3 pre-arranged by parity
            int hb = 3*m - 1;
            int wq, off0;
            if (m <= 0) { wq = 0; off0 = 0; }
            else        { wq = hb >> 1; off0 = 1 + (hb & 1); if (wq > WQMAX) wq = WQMAX; }
            unsigned w0 = imgw[wq], w1 = imgw[wq+1], w2 = imgw[wq+2];
            unsigned pa, pb; unsigned f3h;
            if (off0 == 0)      { pa = (w0 & 0xffffu) | (w0 << 16); pb = (w0 >> 16) | (w1 << 16); f3h = w2 & 0xffffu; }
            else if (off0 == 1) { pa = w0;                          pb = w1;                      f3h = w2 & 0xffffu; }
            else                { pa = (w0 >> 16) | (w1 << 16);     pb = (w1 >> 16) | (w2 << 16); f3h = w2 >> 16; }
            if (m >= NPIX - 1) f3h = (pb >> 16);   // f3 := f2 at the last pixel
            pk01[s] = pa; pk12[s] = pb;
            if (s & 1) pk3[s >> 1] |= (f3h << 16);
            else       pk3[s >> 1]  = f3h;
        }
    }

    #pragma unroll
    for (int lvl = 0; lvl < K_ITERS; ++lvl) {
        float (* __restrict__ lgc)[IC] = lgl[lvl & 1];
        float (* __restrict__ lgn)[IC] = lgl[(lvl & 1) ^ 1];
        float (* __restrict__ sgc)[IC] = sgl[lvl & 1];
        const int ms = 2*lvl + 1;
        const bool jokB = (j >= ms && j < IC - ms);
        // --- pass B: sig from r (own-cell reg, row-i rll neighbors) + staged img ---
        {
            int m = m00;
            #pragma unroll
            for (int s = 0; s < NSLOT; ++s, m += 8*WP) {
                int i = i0 + 8*s;
                float sv = 0.0f;
                if (jokB && i >= ms && i < IY - ms && (unsigned)m < (unsigned)NPIX) {
                    float r0 = rB[s];
                    float rm = (m > 0)        ? rll[i][j-1] : r0;
                    float rp = (m < NPIX - 1) ? rll[i][j+1] : r0;
                    union { unsigned u; half_t h[2]; } ua, ub, uc;
                    ua.u = pk01[s]; ub.u = pk12[s]; uc.u = pk3[s >> 1];
                    float fm1 = (float)ua.h[0];
                    float f0  = (float)ua.h[1];
                    float f1  = (float)ub.h[0];
                    float f2  = (float)ub.h[1];
                    float f3  = (float)uc.h[s & 1];
                    float dm1 = (fm1 - A2) * rm + A2;
                    float d0  = (f0  - A0) * r0 + A0;
                    float d1  = (f1  - A1) * r0 + A1;
                    float d2  = (f2  - A2) * r0 + A2;
                    float d3  = (f3  - A0) * rp + A0;
                    float y0 = 0.5f * (d1 - dm1);
                    float y1 = 0.5f * (d2 - d0);
                    float y2 = 0.5f * (d3 - d1);
                    if (m == 0      ) y0 = d1 - d0;
                    if (m == N3     ) y0 = d1 - d0;
                    if (m == 2*N3   ) y0 = d1 - d0;
                    if (m == N3 - 1 ) y2 = d2 - d1;
                    if (m == 2*N3-1 ) y2 = d2 - d1;
                    if (m == NPIX-1 ) y2 = d2 - d1;
                    float l2 = sqrtf(y0*y0 + y1*y1 + y2*y2);
                    sv = fast_rcp(1.0f + __expf(48.0f * (l2 - 0.1f)));
                }
                sgc[i][j] = sv;
            }
        }
        __syncthreads();   // covers: B's sgl writes -> C's cross-row sgl reads,
                           // and prev C's lgl writes -> this C's cross-row lgl reads
        // --- pass C: t update; w0/r from registers; fully unrolled for ILP ---
        const int mt = 2*lvl + 2;
        const bool jokC = (j >= mt && j < IC - mt);
        {
            int m = m00;
            #pragma unroll
            for (int s = 0; s < NSLOT; ++s, m += 8*WP) {
                int i = i0 + 8*s;
                if (jokC && i >= mt && i < IY - mt && (unsigned)m < (unsigned)NPIX) {
                    int a = rbase + i + da;
                    float lgC = lgc[i][j];
                    float acc = 0.0f;
                    if (bW)
                        acc += (lgC - (bW2 ? lgc[i][j-2] : 0.0f)) * sgc[i][j-1];
                    if (bE)
                        acc -= ((bE2 ? lgc[i][j+2] : 0.0f) - lgC) * sgc[i][j+1];
                    if (a <= HP-2)
                        acc += (lgC - ((a <= HP-3) ? lgc[i+2][j] : 0.0f)) * sgc[i+1][j];
                    if (a >= 1)
                        acc -= (((a >= 2) ? lgc[i-2][j] : 0.0f) - lgC) * sgc[i-1][j];
                    float rr = rB[s];
                    float rw = (rr <= 0.0f) ? 1e7f : rr;    // rcp(guard(t))
                    float v = w0r[s] - 0.001f * 2.0f * acc * rw;
                    if (lvl == K_ITERS - 1) {
                        if (col < WP) tout[m] = v;          // interior => col>=0, m valid
                    } else {
                        float rv = fast_rcp(v);
                        w0r[s] = (v <= 0.0f) ? EPSV : v;
                        rB[s]  = rv;
                        lgn[i][j] = __logf(v <= 0.0f ? EPSV : v);
                        rll[i][j] = rv;
                    }
                }
            }
        }
        // no barrier: next B depends only on same-wave state (rll row i, regs);
        // sgl WAR removed by double-buffer; lgl WAR covered by next B->C barrier
    }
}

// ---------------------------------------------------------------------------
// final dehaze from t_100
// ---------------------------------------------------------------------------
__global__ void out_kernel(const float* __restrict__ t, const half_t* __restrict__ img_c,
                           const float* __restrict__ A, float* __restrict__ out) {
    int m = blockIdx.x * blockDim.x + threadIdx.x;
    if (m >= NPIX) return;
    float tv = t[m];
    float A0 = A[0], A1 = A[1], A2 = A[2];
    float r = 1.0f / tv;               // precise div for the final output
    out[3*m+0] = ((float)img_c[3*m+0] - A0) * r + A0;
    out[3*m+1] = ((float)img_c[3*m+1] - A1) * r + A1;
    out[3*m+2] = ((float)img_c[3*m+2] - A2) * r + A2;
}

extern "C" void kernel_launch(void* const* d_in, const int* in_sizes, int n_in,
                              void* d_out, int out_size, void* d_ws, size_t ws_size,
                              hipStream_t stream) {
    const float* img = (const float*)d_in[0];
    const float* A   = (const float*)d_in[1];
    // workspace: t_a[N] f32 | t_b[N] f32 | img_c[3N] f16 (+slack)
    float*  ws    = (float*)d_ws;
    float*  t_a   = ws;
    float*  t_b   = t_a + NPIX;
    half_t* img_c = (half_t*)(t_b + NPIX);

    dim3 blk2(256, 1, 1);
    dim3 grd2((WP + 255) / 256, HP, 1);
    int blk1 = 256;
    int grd1 = (NPIX + blk1 - 1) / blk1;

    hipLaunchKernelGGL(init_kernel, grd2, blk2, 0, stream, img, A, img_c, t_a);

    float* tsrc = t_a;
    float* tdst = t_b;
    for (int d = 0; d < 25; ++d) {               // 25 dispatches x 4 iters = 100
        hipLaunchKernelGGL(tb_kernel, dim3(NBX, NBY), dim3(TBT), 0, stream,
                           tsrc, tdst, img_c, A);
        float* tmp = tsrc; tsrc = tdst; tdst = tmp;
    }
    hipLaunchKernelGGL(out_kernel, dim3(grd1), dim3(blk1), 0, stream,
                       tsrc, img_c, A, (float*)d_out);
}

// Round 27
// 718.480 us; speedup vs baseline: 1.2302x; 1.0781x over previous
//
#include <hip/hip_runtime.h>

// Problem constants (shapes fixed by the reference)
#define HP    1017
#define WP    1017
#define NPIX  (HP*WP)          // 1034289
#define N3    (NPIX/3)         // 344763
#define W_IMG 1024
#define EPSV  1e-7f

// temporal blocking geometry: SQUARE tile, 64x64, K=4
#define K_ITERS 4
#define RY   48
#define CW   48
#define HALO 8
#define IY   64
#define IC   64
#define NBX  22                // 22*48 = 1056 >= 1017
#define NBY  22
#define TBT  512
#define NSLOT 8                // 64*64 = 4096 = 512*8
#define WQMAX 1551431

typedef _Float16 half_t;

__device__ __forceinline__ float fast_rcp(float x)  { return __builtin_amdgcn_rcpf(x); }
__device__ __forceinline__ float fast_sqrt(float x) { return __builtin_amdgcn_sqrtf(x); }

// ---------------------------------------------------------------------------
// init: t0 = tlb = max_c(1 - center/A), and pack img_c (fp16) contiguously
// ---------------------------------------------------------------------------
__global__ void init_kernel(const float* __restrict__ img, const float* __restrict__ A,
                            half_t* __restrict__ img_c, float* __restrict__ t0) {
    int b = blockIdx.x * blockDim.x + threadIdx.x;
    int a = blockIdx.y;
    if (b >= WP) return;
    int m = a * WP + b;
    float A0 = A[0], A1 = A[1], A2 = A[2];
    const float* src = img + ((size_t)a * W_IMG + b) * 3;
    img_c[3*m+0] = (half_t)src[0];
    img_c[3*m+1] = (half_t)src[1];
    img_c[3*m+2] = (half_t)src[2];
    const float* cen = img + ((size_t)(a+3) * W_IMG + (b+3)) * 3;
    float t = 1.0f - cen[0] / A0;
    t = fmaxf(t, 1.0f - cen[1] / A1);
    t = fmaxf(t, 1.0f - cen[2] / A2);
    t0[m] = t;
}

// ---------------------------------------------------------------------------
// temporal-blocked kernel: 4 GD iterations in LDS (R24/R26 structure; only
// change: sqrtf -> v_sqrt_f32 single instruction in pass B).
// ---------------------------------------------------------------------------
__global__ __launch_bounds__(TBT, 4) void tb_kernel(
    const float* __restrict__ tin, float* __restrict__ tout,
    const half_t* __restrict__ img_c, const float* __restrict__ A)
{
    __shared__ float lgl[2][IY][IC];    // 32 KiB (ping-pong per level)
    __shared__ float sgl[2][IY][IC];    // 32 KiB (ping-pong per level)
    __shared__ float rll[IY][IC];       // 16 KiB  => 80 KiB total, 2 blocks/CU

    const int tid   = threadIdx.x;
    const int i0    = tid >> 6;         // 0..7 = wave id; wave w owns rows i with i&7==w
    const int j     = tid & 63;         // lane = fixed column
    const int rbase = blockIdx.y * RY - HALO;
    const int cbase = blockIdx.x * CW - HALO;
    const int col   = cbase + j;
    const float A0 = A[0], A1 = A[1], A2 = A[2];

    // hoisted column-wrap: cell (i,j) is flat pixel (arow+da, b)
    const int da = (col < 0) ? -1 : ((col >= WP) ? 1 : 0);
    const int b  = col - da * WP;
    const bool bW  = (b >= 1), bW2 = (b >= 2);
    const bool bE  = (b <= WP-2), bE2 = (b <= WP-3);
    const int m00 = (rbase + i0) * WP + col;

    const unsigned* imgw = (const unsigned*)img_c;
    unsigned pk01[NSLOT], pk12[NSLOT], pk3[NSLOT/2];
    float w0r[NSLOT];                   // guard(t) at own cell
    float rB[NSLOT];                    // rcp(raw t) at own cell (f32)

    // ---- load t_k -> lg + r + regs; stage img window into registers ----
    // No barrier after: B(0) reads only row-i rll (own wave) + registers.
    {
        int m = m00;
        #pragma unroll
        for (int s = 0; s < NSLOT; ++s, m += 8*WP) {
            int i = i0 + 8*s;
            float v = 1.0f;
            if ((unsigned)m < (unsigned)NPIX) v = tin[m];
            float rv = fast_rcp(v);
            w0r[s] = (v <= 0.0f) ? EPSV : v;
            rB[s]  = rv;
            rll[i][j]    = rv;
            lgl[0][i][j] = __logf(v <= 0.0f ? EPSV : v);
            // img window: halfs 3m-1 .. 3m+3 pre-arranged by parity
            int hb = 3*m - 1;
            int wq, off0;
            if (m <= 0) { wq = 0; off0 = 0; }
            else        { wq = hb >> 1; off0 = 1 + (hb & 1); if (wq > WQMAX) wq = WQMAX; }
            unsigned w0 = imgw[wq], w1 = imgw[wq+1], w2 = imgw[wq+2];
            unsigned pa, pb; unsigned f3h;
            if (off0 == 0)      { pa = (w0 & 0xffffu) | (w0 << 16); pb = (w0 >> 16) | (w1 << 16); f3h = w2 & 0xffffu; }
            else if (off0 == 1) { pa = w0;                          pb = w1;                      f3h = w2 & 0xffffu; }
            else                { pa = (w0 >> 16) | (w1 << 16);     pb = (w1 >> 16) | (w2 << 16); f3h = w2 >> 16; }
            if (m >= NPIX - 1) f3h = (pb >> 16);   // f3 := f2 at the last pixel
            pk01[s] = pa; pk12[s] = pb;
            if (s & 1) pk3[s >> 1] |= (f3h << 16);
            else       pk3[s >> 1]  = f3h;
        }
    }

    #pragma unroll
    for (int lvl = 0; lvl < K_ITERS; ++lvl) {
        float (* __restrict__ lgc)[IC] = lgl[lvl & 1];
        float (* __restrict__ lgn)[IC] = lgl[(lvl & 1) ^ 1];
        float (* __restrict__ sgc)[IC] = sgl[lvl & 1];
        const int ms = 2*lvl + 1;
        const bool jokB = (j >= ms && j < IC - ms);
        // --- pass B: sig from r (own-cell reg, row-i rll neighbors) + staged img ---
        {
            int m = m00;
            #pragma unroll
            for (int s = 0; s < NSLOT; ++s, m += 8*WP) {
                int i = i0 + 8*s;
                float sv = 0.0f;
                if (jokB && i >= ms && i < IY - ms && (unsigned)m < (unsigned)NPIX) {
                    float r0 = rB[s];
                    float rm = (m > 0)        ? rll[i][j-1] : r0;
                    float rp = (m < NPIX - 1) ? rll[i][j+1] : r0;
                    union { unsigned u; half_t h[2]; } ua, ub, uc;
                    ua.u = pk01[s]; ub.u = pk12[s]; uc.u = pk3[s >> 1];
                    float fm1 = (float)ua.h[0];
                    float f0  = (float)ua.h[1];
                    float f1  = (float)ub.h[0];
                    float f2  = (float)ub.h[1];
                    float f3  = (float)uc.h[s & 1];
                    float dm1 = (fm1 - A2) * rm + A2;
                    float d0  = (f0  - A0) * r0 + A0;
                    float d1  = (f1  - A1) * r0 + A1;
                    float d2  = (f2  - A2) * r0 + A2;
                    float d3  = (f3  - A0) * rp + A0;
                    float y0 = 0.5f * (d1 - dm1);
                    float y1 = 0.5f * (d2 - d0);
                    float y2 = 0.5f * (d3 - d1);
                    if (m == 0      ) y0 = d1 - d0;
                    if (m == N3     ) y0 = d1 - d0;
                    if (m == 2*N3   ) y0 = d1 - d0;
                    if (m == N3 - 1 ) y2 = d2 - d1;
                    if (m == 2*N3-1 ) y2 = d2 - d1;
                    if (m == NPIX-1 ) y2 = d2 - d1;
                    float l2 = fast_sqrt(y0*y0 + y1*y1 + y2*y2);
                    sv = fast_rcp(1.0f + __expf(48.0f * (l2 - 0.1f)));
                }
                sgc[i][j] = sv;
            }
        }
        __syncthreads();   // covers: B's sgl writes -> C's cross-row sgl reads,
                           // and prev C's lgl writes -> this C's cross-row lgl reads
        // --- pass C: t update; w0/r from registers; fully unrolled for ILP ---
        const int mt = 2*lvl + 2;
        const bool jokC = (j >= mt && j < IC - mt);
        {
            int m = m00;
            #pragma unroll
            for (int s = 0; s < NSLOT; ++s, m += 8*WP) {
                int i = i0 + 8*s;
                if (jokC && i >= mt && i < IY - mt && (unsigned)m < (unsigned)NPIX) {
                    int a = rbase + i + da;
                    float lgC = lgc[i][j];
                    float acc = 0.0f;
                    if (bW)
                        acc += (lgC - (bW2 ? lgc[i][j-2] : 0.0f)) * sgc[i][j-1];
                    if (bE)
                        acc -= ((bE2 ? lgc[i][j+2] : 0.0f) - lgC) * sgc[i][j+1];
                    if (a <= HP-2)
                        acc += (lgC - ((a <= HP-3) ? lgc[i+2][j] : 0.0f)) * sgc[i+1][j];
                    if (a >= 1)
                        acc -= (((a >= 2) ? lgc[i-2][j] : 0.0f) - lgC) * sgc[i-1][j];
                    float rr = rB[s];
                    float rw = (rr <= 0.0f) ? 1e7f : rr;    // rcp(guard(t))
                    float v = w0r[s] - 0.001f * 2.0f * acc * rw;
                    if (lvl == K_ITERS - 1) {
                        if (col < WP) tout[m] = v;          // interior => col>=0, m valid
                    } else {
                        float rv = fast_rcp(v);
                        w0r[s] = (v <= 0.0f) ? EPSV : v;
                        rB[s]  = rv;
                        lgn[i][j] = __logf(v <= 0.0f ? EPSV : v);
                        rll[i][j] = rv;
                    }
                }
            }
        }
        // no barrier: next B depends only on same-wave state (rll row i, regs);
        // sgl WAR removed by double-buffer; lgl WAR covered by next B->C barrier
    }
}

// ---------------------------------------------------------------------------
// final dehaze from t_100
// ---------------------------------------------------------------------------
__global__ void out_kernel(const float* __restrict__ t, const half_t* __restrict__ img_c,
                           const float* __restrict__ A, float* __restrict__ out) {
    int m = blockIdx.x * blockDim.x + threadIdx.x;
    if (m >= NPIX) return;
    float tv = t[m];
    float A0 = A[0], A1 = A[1], A2 = A[2];
    float r = 1.0f / tv;               // precise div for the final output
    out[3*m+0] = ((float)img_c[3*m+0] - A0) * r + A0;
    out[3*m+1] = ((float)img_c[3*m+1] - A1) * r + A1;
    out[3*m+2] = ((float)img_c[3*m+2] - A2) * r + A2;
}

extern "C" void kernel_launch(void* const* d_in, const int* in_sizes, int n_in,
                              void* d_out, int out_size, void* d_ws, size_t ws_size,
                              hipStream_t stream) {
    const float* img = (const float*)d_in[0];
    const float* A   = (const float*)d_in[1];
    // workspace: t_a[N] f32 | t_b[N] f32 | img_c[3N] f16 (+slack)
    float*  ws    = (float*)d_ws;
    float*  t_a   = ws;
    float*  t_b   = t_a + NPIX;
    half_t* img_c = (half_t*)(t_b + NPIX);

    dim3 blk2(256, 1, 1);
    dim3 grd2((WP + 255) / 256, HP, 1);
    int blk1 = 256;
    int grd1 = (NPIX + blk1 - 1) / blk1;

    hipLaunchKernelGGL(init_kernel, grd2, blk2, 0, stream, img, A, img_c, t_a);

    float* tsrc = t_a;
    float* tdst = t_b;
    for (int d = 0; d < 25; ++d) {               // 25 dispatches x 4 iters = 100
        hipLaunchKernelGGL(tb_kernel, dim3(NBX, NBY), dim3(TBT), 0, stream,
                           tsrc, tdst, img_c, A);
        float* tmp = tsrc; tsrc = tdst; tdst = tmp;
    }
    hipLaunchKernelGGL(out_kernel, dim3(grd1), dim3(blk1), 0, stream,
                       tsrc, img_c, A, (float*)d_out);
}